// Round 4
// baseline (205.118 us; speedup 1.0000x reference)
//
#include <hip/hip_runtime.h>
#include <cmath>

#define NB 128     // batch
#define CC 1024    // classes
#define CAP 64     // max nnz per row of R (expected ~11, P(>63) negligible)

// ---------------------------------------------------------------------------
// Kernel 1: compact each row of R (1024x1024, ~1% dense + diagonal) into a
// padded CSR. Order within a row is arbitrary (max is order-independent).
// ---------------------------------------------------------------------------
__global__ void build_csr(const float* __restrict__ R, int* __restrict__ cnt,
                          int* __restrict__ cols, float* __restrict__ vals) {
    __shared__ int s_cnt;
    const int i = blockIdx.x;
    if (threadIdx.x == 0) s_cnt = 0;
    __syncthreads();
    #pragma unroll
    for (int k = 0; k < CC / 256; ++k) {
        const int j = threadIdx.x + k * 256;
        const float v = R[i * CC + j];
        if (v != 0.0f) {
            const int pos = atomicAdd(&s_cnt, 1);
            if (pos < CAP) { cols[i * CAP + pos] = j; vals[i * CAP + pos] = v; }
        }
    }
    __syncthreads();
    if (threadIdx.x == 0) cnt[i] = min(s_cnt, CAP);
}

// ---------------------------------------------------------------------------
// Kernel 2: p = sigmoid(h), py = p * y
// ---------------------------------------------------------------------------
__global__ void sigmoid_kernel(const float* __restrict__ h, const int* __restrict__ y,
                               float* __restrict__ p, float* __restrict__ py) {
    const int t = blockIdx.x * 256 + threadIdx.x;
    const float pv = 1.0f / (1.0f + expf(-h[t]));
    p[t]  = pv;
    py[t] = pv * (float)y[t];
}

// ---------------------------------------------------------------------------
// Kernel 3: mcm[n,i] = max_j R[i,j]*p[n,j]  (sparse over row i of R),
//           mcm_pos likewise on py; h_star = (1-y)*mcm + y*mcm_pos.
// Thread t -> n = t>>10, i = t&1023 (coalesced writes; p-row L1-resident).
// Max starts at 0.0f: identical to dense max since all-zero products exist
// and all stored products are >= 0.
// ---------------------------------------------------------------------------
__global__ void mcm_kernel(const float* __restrict__ p, const float* __restrict__ py,
                           const int* __restrict__ y,
                           const int* __restrict__ cnt, const int* __restrict__ cols,
                           const float* __restrict__ vals,
                           float* __restrict__ mcm_out, float* __restrict__ hstar) {
    const int t = blockIdx.x * 256 + threadIdx.x;
    const int n = t >> 10;
    const int i = t & (CC - 1);
    const int rc = cnt[i];
    const float* __restrict__ prow  = p  + n * CC;
    const float* __restrict__ pyrow = py + n * CC;
    float m = 0.0f, mp = 0.0f;
    for (int k = 0; k < rc; ++k) {
        const int   j = cols[i * CAP + k];
        const float v = vals[i * CAP + k];
        m  = fmaxf(m,  v * prow[j]);
        mp = fmaxf(mp, v * pyrow[j]);
    }
    mcm_out[t] = m;
    const float yf = (float)y[t];
    hstar[t] = (1.0f - yf) * m + yf * mp;
}

// ---------------------------------------------------------------------------
// Kernel 4: all reductions. One block, 1024 threads (one per class c).
// Per-class: intersection, cardinality, present, plus BCE partial sum.
// Then block-reduce dice terms and bce; thread 0 writes the loss scalar.
// ---------------------------------------------------------------------------
__global__ void reduce_kernel(const float* __restrict__ hstar, const int* __restrict__ y,
                              float* __restrict__ out) {
    const int c = threadIdx.x;
    float I = 0.0f, card = 0.0f, bce = 0.0f;
    int pres = 0;
    for (int n = 0; n < NB; ++n) {
        const float hv = hstar[n * CC + c];
        const int   yv = y[n * CC + c];
        const float yf = (float)yv;
        I    += hv * yf;
        card += hv + yf;
        pres |= yv;
        const float lg = (yv != 0) ? logf(hv) : log1pf(-hv);
        bce += fmaxf(lg, -100.0f);
    }
    float dice = pres ? (1.0f - 2.0f * I / fmaxf(card, 1e-7f)) : 0.0f;

    // block reduction (16 waves of 64)
    #pragma unroll
    for (int off = 32; off > 0; off >>= 1) {
        dice += __shfl_down(dice, off);
        bce  += __shfl_down(bce, off);
    }
    __shared__ float sd[16], sb[16];
    const int wid = threadIdx.x >> 6, lane = threadIdx.x & 63;
    if (lane == 0) { sd[wid] = dice; sb[wid] = bce; }
    __syncthreads();
    if (threadIdx.x == 0) {
        float ds = 0.0f, bs = 0.0f;
        #pragma unroll
        for (int w = 0; w < 16; ++w) { ds += sd[w]; bs += sb[w]; }
        out[0] = ds / (float)CC - bs / (float)(NB * CC);
    }
}

// ---------------------------------------------------------------------------
extern "C" void kernel_launch(void* const* d_in, const int* in_sizes, int n_in,
                              void* d_out, int out_size, void* d_ws, size_t ws_size,
                              hipStream_t stream) {
    const float* h = (const float*)d_in[0];
    const int*   y = (const int*)d_in[1];
    const float* R = (const float*)d_in[2];
    float* out = (float*)d_out;       // out[0]=loss, out[1..]=mcm (N,C) row-major

    // workspace layout (floats unless noted)
    float* p     = (float*)d_ws;            // N*C
    float* py    = p  + NB * CC;            // N*C
    float* hstar = py + NB * CC;            // N*C
    int*   cnt   = (int*)(hstar + NB * CC); // C
    int*   cols  = cnt + CC;                // C*CAP
    float* vals  = (float*)(cols + CC * CAP); // C*CAP

    build_csr<<<CC, 256, 0, stream>>>(R, cnt, cols, vals);
    sigmoid_kernel<<<(NB * CC) / 256, 256, 0, stream>>>(h, y, p, py);
    mcm_kernel<<<(NB * CC) / 256, 256, 0, stream>>>(p, py, y, cnt, cols, vals,
                                                    out + 1, hstar);
    reduce_kernel<<<1, 1024, 0, stream>>>(hstar, y, out);
}

// Round 8
// 85.835 us; speedup vs baseline: 2.3897x; 2.3897x over previous
//
#include <hip/hip_runtime.h>
#include <cmath>

#define NB 128     // batch
#define CC 1024    // classes
#define CAP 64     // max nnz per row of R (expected ~11, P(>63) negligible)

// ---------------------------------------------------------------------------
// Kernel 1 (prep): fused three-way by blockIdx.x
//   [0, 1024)      : CSR-compact row b of R (float4 scan + shared-atomic)
//   [1024, 1152)   : p = sigmoid(h), py = p*y  (float4 / int4, 4 elem/thread)
//   [1152, 1168)   : zero the 4096-word accumulator region (accI|accC|accB)
// ---------------------------------------------------------------------------
__global__ void prep_kernel(const float* __restrict__ R,
                            const float* __restrict__ h,
                            const int* __restrict__ y,
                            int* __restrict__ cnt, int* __restrict__ cols,
                            float* __restrict__ vals,
                            float* __restrict__ p, float* __restrict__ py,
                            float* __restrict__ acc) {
    const int b = blockIdx.x, tx = threadIdx.x;
    if (b < CC) {
        __shared__ int s_cnt;
        if (tx == 0) s_cnt = 0;
        __syncthreads();
        const float4 v4 = ((const float4*)(R + b * CC))[tx];
        const int j0 = tx * 4;
        #pragma unroll
        for (int u = 0; u < 4; ++u) {
            const float v = (u == 0) ? v4.x : (u == 1) ? v4.y : (u == 2) ? v4.z : v4.w;
            if (v != 0.0f) {
                const int pos = atomicAdd(&s_cnt, 1);
                if (pos < CAP) { cols[b * CAP + pos] = j0 + u; vals[b * CAP + pos] = v; }
            }
        }
        __syncthreads();
        if (tx == 0) cnt[b] = min(s_cnt, CAP);
    } else if (b < CC + 128) {
        const int t = (b - CC) * 256 + tx;            // float4 index, covers NB*CC/4
        const float4 hv = ((const float4*)h)[t];
        const int4   yv = ((const int4*)y)[t];
        float4 pv, pyv;
        pv.x = 1.0f / (1.0f + expf(-hv.x));  pyv.x = pv.x * (float)yv.x;
        pv.y = 1.0f / (1.0f + expf(-hv.y));  pyv.y = pv.y * (float)yv.y;
        pv.z = 1.0f / (1.0f + expf(-hv.z));  pyv.z = pv.z * (float)yv.z;
        pv.w = 1.0f / (1.0f + expf(-hv.w));  pyv.w = pv.w * (float)yv.w;
        ((float4*)p)[t]  = pv;
        ((float4*)py)[t] = pyv;
    } else {
        const int idx = (b - CC - 128) * 256 + tx;    // 16*256 = 4096 words
        acc[idx] = 0.0f;
    }
}

// ---------------------------------------------------------------------------
// Kernel 2 (mcm_fused): per (n,i) thread —
//   mcm  = max_j R[i,j]*p[n,j]   (sparse row i; seed 0.0 == dense max since
//                                 all products >= 0 and zero products exist)
//   h*   = y ? mcm_pos : mcm
//   writes mcm to out+1; accumulates dice intersection/cardinality per class
//   (float atomics, order-independent up to ~1e-6) and block-reduced BCE.
//   present[c] later recovered as accI[c] > 0 (exact: y=1 => h* >= p > 0).
// ---------------------------------------------------------------------------
__global__ void mcm_fused(const float* __restrict__ p, const float* __restrict__ py,
                          const int* __restrict__ y,
                          const int* __restrict__ cnt, const int* __restrict__ cols,
                          const float* __restrict__ vals,
                          float* __restrict__ mcm_out,
                          float* __restrict__ accI, float* __restrict__ accC,
                          float* __restrict__ accB) {
    const int t = blockIdx.x * 256 + threadIdx.x;
    const int n = t >> 10;
    const int i = t & (CC - 1);
    const int rc = cnt[i];
    const float* __restrict__ prow  = p  + n * CC;
    const float* __restrict__ pyrow = py + n * CC;
    float m = 0.0f, mp = 0.0f;
    for (int k = 0; k < rc; ++k) {
        const int   j = cols[i * CAP + k];
        const float v = vals[i * CAP + k];
        m  = fmaxf(m,  v * prow[j]);
        mp = fmaxf(mp, v * pyrow[j]);
    }
    mcm_out[t] = m;

    const int   yv = y[t];
    const float yf = (float)yv;
    const float hv = yv ? mp : m;                 // (1-yf)*m + yf*mp, y in {0,1}

    if (yv) atomicAdd(accI + i, hv);              // intersection contribution
    atomicAdd(accC + i, hv + yf);                 // cardinality contribution

    float lg = yv ? logf(hv) : log1pf(-hv);
    lg = fmaxf(lg, -100.0f);
    // block-reduce lg over 256 threads (4 waves) then one atomic per block
    #pragma unroll
    for (int off = 32; off > 0; off >>= 1) lg += __shfl_down(lg, off);
    __shared__ float sb[4];
    const int wid = threadIdx.x >> 6, lane = threadIdx.x & 63;
    if (lane == 0) sb[wid] = lg;
    __syncthreads();
    if (threadIdx.x == 0)
        atomicAdd(accB, sb[0] + sb[1] + sb[2] + sb[3]);
}

// ---------------------------------------------------------------------------
// Kernel 3 (finalize): 1 block x 1024 threads, loop length 1.
// dice term per class from accI/accC; reduce; combine with BCE scalar.
// ---------------------------------------------------------------------------
__global__ void finalize(const float* __restrict__ accI, const float* __restrict__ accC,
                         const float* __restrict__ accB, float* __restrict__ out) {
    const int c = threadIdx.x;
    const float I = accI[c], card = accC[c];
    float dice = (I > 0.0f) ? (1.0f - 2.0f * I / fmaxf(card, 1e-7f)) : 0.0f;
    #pragma unroll
    for (int off = 32; off > 0; off >>= 1) dice += __shfl_down(dice, off);
    __shared__ float sd[16];
    const int wid = threadIdx.x >> 6, lane = threadIdx.x & 63;
    if (lane == 0) sd[wid] = dice;
    __syncthreads();
    if (threadIdx.x == 0) {
        float ds = 0.0f;
        #pragma unroll
        for (int w = 0; w < 16; ++w) ds += sd[w];
        out[0] = ds / (float)CC - accB[0] / (float)(NB * CC);
    }
}

// ---------------------------------------------------------------------------
extern "C" void kernel_launch(void* const* d_in, const int* in_sizes, int n_in,
                              void* d_out, int out_size, void* d_ws, size_t ws_size,
                              hipStream_t stream) {
    const float* h = (const float*)d_in[0];
    const int*   y = (const int*)d_in[1];
    const float* R = (const float*)d_in[2];
    float* out = (float*)d_out;       // out[0]=loss, out[1..]=mcm (N,C) row-major

    // workspace layout
    float* p    = (float*)d_ws;                 // NB*CC
    float* py   = p + NB * CC;                  // NB*CC
    int*   cnt  = (int*)(py + NB * CC);         // CC
    int*   cols = cnt + CC;                     // CC*CAP
    float* vals = (float*)(cols + CC * CAP);    // CC*CAP
    float* acc  = vals + CC * CAP;              // 4096: accI[1024]|accC[1024]|accB[1]|pad
    float* accI = acc;
    float* accC = acc + CC;
    float* accB = acc + 2 * CC;

    prep_kernel<<<CC + 128 + 16, 256, 0, stream>>>(R, h, y, cnt, cols, vals, p, py, acc);
    mcm_fused<<<(NB * CC) / 256, 256, 0, stream>>>(p, py, y, cnt, cols, vals,
                                                   out + 1, accI, accC, accB);
    finalize<<<1, 1024, 0, stream>>>(accI, accC, accB, out);
}